// Round 14
// baseline (486.581 us; speedup 1.0000x reference)
//
#include <hip/hip_runtime.h>
#include <math.h>

static constexpr int NN   = 20000;
static constexpr int TT   = 6;
static constexpr int EE   = 640000;
static constexpr int CINC = 3;
static constexpr int HH   = 64;
static constexpr int RB   = 8;    // nodes per wave in the dense kernels
static constexpr int GW   = 4;    // waves per block in gru6
static constexpr int BKSH = 7;    // 128 nodes per bucket
static constexpr int NBKT = (NN + (1 << BKSH) - 1) >> BKSH;  // 157
static constexpr int CAP  = 6144; // bucket capacity (expected 4096, +32 sigma)
static constexpr int EPB  = 4096; // edges per workgroup in bin phase

// ---- bf16 helpers (storage = ushort) ------------------------------------
__device__ inline unsigned short f2bf(float f) {
    unsigned u = __float_as_uint(f);
    unsigned r = (u + 0x7FFFu + ((u >> 16) & 1u)) >> 16;  // RTNE
    return (unsigned short)r;
}
__device__ inline float bflo(unsigned u) { return __uint_as_float(u << 16); }
__device__ inline float bfhi(unsigned u) { return __uint_as_float(u & 0xFFFF0000u); }

// ---- phase 1: bin edges into 157 coarse buckets (packed dstLocal|src) ----
__global__ void bin6_kernel(const int* __restrict__ edges, int* __restrict__ gcur,
                            int* __restrict__ bucketArr) {
    int t = blockIdx.y;
    __shared__ int hist[NBKT];
    __shared__ int base[NBKT];
    int tid = threadIdx.x;
    for (int i = tid; i < NBKT; i += 256) hist[i] = 0;
    __syncthreads();
    const int* src = edges + (size_t)t * 2 * EE;
    const int* dst = src + EE;
    int e0 = blockIdx.x * EPB;
    int pack[16], loff[16], bkt[16];
    int m = 0;
#pragma unroll
    for (int i = 0; i < 16; ++i) {
        int e = e0 + tid + i * 256;
        if (e < EE) {
            int s = src[e], d = dst[e];
            int b = d >> BKSH;
            bkt[i] = b;
            pack[i] = ((d & 127) << 16) | s;
            loff[i] = atomicAdd(&hist[b], 1);
            m = i + 1;
        }
    }
    __syncthreads();
    for (int i = tid; i < NBKT; i += 256)
        base[i] = atomicAdd(&gcur[t * NBKT + i], hist[i]);
    __syncthreads();
    for (int i = 0; i < m; ++i) {
        int b = bkt[i];
        int pos = base[b] + loff[i];
        if (pos < CAP)
            bucketArr[(size_t)(t * NBKT + b) * CAP + pos] = pack[i];
    }
}

// ---- per-node degree from buckets: LDS histogram, coalesced write -------
__global__ void bucket_count6_kernel(const int* __restrict__ gcur,
                                     const int* __restrict__ bucketArr,
                                     int* __restrict__ cnt6) {
    int bk = blockIdx.x, t = blockIdx.y;
    __shared__ int hist[128];
    int tid = threadIdx.x;
    if (tid < 128) hist[tid] = 0;
    __syncthreads();
    int ecnt = gcur[t * NBKT + bk];
    if (ecnt > CAP) ecnt = CAP;
    const int* barr = bucketArr + (size_t)(t * NBKT + bk) * CAP;
    for (int e = tid; e < ecnt; e += 256) atomicAdd(&hist[barr[e] >> 16], 1);
    __syncthreads();
    int n = (bk << BKSH) + tid;
    if (tid < 128 && n < NN) cnt6[t * NN + n] = hist[tid];
}

// 6 blocks (one per t), 1024 threads: exclusive scan -> rowptr, plus dinv
__global__ void scan6_kernel(const int* __restrict__ cnt6, int* __restrict__ rowptr6,
                             float* __restrict__ dinv6) {
    int t = blockIdx.x;
    const int* cnt = cnt6 + t * NN;
    int* rowptr = rowptr6 + t * (NN + 1);
    float* dinv = dinv6 + t * NN;
    __shared__ int part[1024];
    const int CHUNK = 20;  // 1024*20 >= NN
    int tid = threadIdx.x;
    int base = tid * CHUNK;
    int local[CHUNK];
    int s = 0;
#pragma unroll
    for (int i = 0; i < CHUNK; ++i) {
        int idx = base + i;
        int v = (idx < NN) ? cnt[idx] : 0;
        local[i] = s;
        s += v;
    }
    part[tid] = s;
    __syncthreads();
    for (int off = 1; off < 1024; off <<= 1) {
        int v = part[tid];
        int add = (tid >= off) ? part[tid - off] : 0;
        __syncthreads();
        part[tid] = v + add;
        __syncthreads();
    }
    int ebase = (tid == 0) ? 0 : part[tid - 1];
#pragma unroll
    for (int i = 0; i < CHUNK; ++i) {
        int idx = base + i;
        if (idx < NN) {
            rowptr[idx] = ebase + local[i];
            dinv[idx] = rsqrtf((float)cnt[idx] + 1.0f);
        }
    }
    if (tid == 1023) rowptr[NN] = part[1023];
}

// ---- phase 2: in-LDS regroup of each bucket into per-node CSR segments ---
__global__ void regroup6_kernel(const int* __restrict__ rowptr6, const int* __restrict__ gcur,
                                const int* __restrict__ bucketArr, int* __restrict__ col6) {
    int bk = blockIdx.x, t = blockIdx.y;
    __shared__ int cursor[128];
    __shared__ int lcol[CAP];  // 24KB
    int tid = threadIdx.x;
    const int* rowptr = rowptr6 + t * (NN + 1);
    int nb0 = bk << BKSH;
    int base = rowptr[nb0];
    if (tid < 128) {
        int n = nb0 + tid;
        if (n < NN) cursor[tid] = rowptr[n] - base;
    }
    __syncthreads();
    int ecnt = gcur[t * NBKT + bk];
    if (ecnt > CAP) ecnt = CAP;
    const int* barr = bucketArr + (size_t)(t * NBKT + bk) * CAP;
    for (int e = tid; e < ecnt; e += 256) {
        int w = barr[e];
        int dl = w >> 16, s = w & 0xFFFF;
        int off = atomicAdd(&cursor[dl], 1);
        lcol[off] = s;
    }
    __syncthreads();
    int* colt = col6 + (size_t)t * EE + base;
    for (int e = tid; e < ecnt; e += 256) colt[e] = lcol[e];
}

// ---- GRU weight repack (bf16): Aw[k*64+jj] = {ir|iz<<16, in|hr<<16}, Bw = hz|hn<<16
__global__ void pack_gru_kernel(const float* __restrict__ wih, const float* __restrict__ whh,
                                uint2* __restrict__ Aw, unsigned* __restrict__ Bw) {
    int idx = blockIdx.x * blockDim.x + threadIdx.x;  // k*64 + jj
    if (idx >= HH * HH) return;
    int k = idx >> 6, jj = idx & 63;
    unsigned w_ir = f2bf(wih[jj * HH + k]);
    unsigned w_iz = f2bf(wih[(64 + jj) * HH + k]);
    unsigned w_in = f2bf(wih[(128 + jj) * HH + k]);
    unsigned w_hr = f2bf(whh[jj * HH + k]);
    unsigned w_hz = f2bf(whh[(64 + jj) * HH + k]);
    unsigned w_hn = f2bf(whh[(128 + jj) * HH + k]);
    Aw[idx] = make_uint2(w_ir | (w_iz << 16), w_in | (w_hr << 16));
    Bw[idx] = w_hz | (w_hn << 16);
}

// ---- y1 for ALL t: y = dinv * (x @ W1), bf16 out ------------------------
__global__ void y1all_kernel(const float* __restrict__ nf, const float* __restrict__ W1,
                             const float* __restrict__ dinv6, unsigned short* __restrict__ Yb) {
    int t = blockIdx.y;
    int gid = blockIdx.x * blockDim.x + threadIdx.x;
    if (gid >= NN * HH) return;
    int node = gid >> 6, hh = gid & 63;
    const float* xr = nf + (size_t)t * NN * CINC + node * CINC;
    float acc = 0.f;
#pragma unroll
    for (int k = 0; k < CINC; ++k) acc = fmaf(xr[k], W1[k * HH + hh], acc);
    Yb[(size_t)t * NN * HH + gid] = f2bf(dinv6[t * NN + node] * acc);
}

// ---- y2 for ALL t: y = dinv * (z @ W2), bf16 in/out ---------------------
__global__ void y2all_kernel(const unsigned short* __restrict__ Zb6, const float* __restrict__ W2,
                             const float* __restrict__ dinv6, unsigned short* __restrict__ Y2all) {
    int t = blockIdx.y;
    const unsigned short* z = Zb6 + (size_t)t * NN * HH;
    const float* dinv = dinv6 + t * NN;
    unsigned short* y = Y2all + (size_t)t * NN * HH;
    int nbase = blockIdx.x * RB;
    int lane = threadIdx.x;
    float acc[RB];
#pragma unroll
    for (int r = 0; r < RB; ++r) acc[r] = 0.f;
    for (int k0 = 0; k0 < 16; ++k0) {
        uint2 zv[RB];
#pragma unroll
        for (int r = 0; r < RB; ++r)
            zv[r] = *(const uint2*)(z + ((size_t)(nbase + r) << 6) + (k0 << 2));
#pragma unroll
        for (int u = 0; u < 4; ++u) {
            float w = W2[(k0 * 4 + u) * HH + lane];
#pragma unroll
            for (int r = 0; r < RB; ++r) {
                float zk = (u == 0) ? bflo(zv[r].x) : (u == 1) ? bfhi(zv[r].x)
                         : (u == 2) ? bflo(zv[r].y) : bfhi(zv[r].y);
                acc[r] = fmaf(zk, w, acc[r]);
            }
        }
    }
#pragma unroll
    for (int r = 0; r < RB; ++r)
        y[((size_t)(nbase + r) << 6) + lane] = f2bf(dinv[nbase + r] * acc[r]);
}

// ---- CSR gather for ALL t (bf16 rows -> bf16 z): z = relu(dinv*(sum+self)+b)
__global__ void gather6_kernel(const int* __restrict__ rowptr6, const int* __restrict__ col6,
                               const float* __restrict__ dinv6, const unsigned short* __restrict__ ybase,
                               const float* __restrict__ b, unsigned short* __restrict__ zbase) {
    int t = blockIdx.y;
    const int* rowptr = rowptr6 + t * (NN + 1);
    const int* col = col6 + (size_t)t * EE;
    const float* dinv = dinv6 + t * NN;
    const unsigned short* y = ybase + (size_t)t * NN * HH;
    unsigned short* z = zbase + (size_t)t * NN * HH;

    int node = (blockIdx.x * blockDim.x + threadIdx.x) >> 6;
    if (node >= NN) return;
    int lane = threadIdx.x & 63;
    int g = lane >> 3, q = lane & 7;
    int ps = rowptr[node], pe = rowptr[node + 1];
    float acc[8];
    if (g == 0) {  // self term
        const uint4 v = *(const uint4*)(y + ((size_t)node << 6) + (q << 3));
        acc[0] = bflo(v.x); acc[1] = bfhi(v.x);
        acc[2] = bflo(v.y); acc[3] = bfhi(v.y);
        acc[4] = bflo(v.z); acc[5] = bfhi(v.z);
        acc[6] = bflo(v.w); acc[7] = bfhi(v.w);
    } else {
#pragma unroll
        for (int j = 0; j < 8; ++j) acc[j] = 0.f;
    }
    for (int p = ps + g; p < pe; p += 8) {
        int c = col[p];
        const uint4 v = *(const uint4*)(y + ((size_t)c << 6) + (q << 3));
        acc[0] += bflo(v.x); acc[1] += bfhi(v.x);
        acc[2] += bflo(v.y); acc[3] += bfhi(v.y);
        acc[4] += bflo(v.z); acc[5] += bfhi(v.z);
        acc[6] += bflo(v.w); acc[7] += bfhi(v.w);
    }
#pragma unroll
    for (int j = 0; j < 8; ++j) {
        acc[j] += __shfl_xor(acc[j], 8);
        acc[j] += __shfl_xor(acc[j], 16);
        acc[j] += __shfl_xor(acc[j], 32);
    }
    if (g == 0) {
        float d = dinv[node];
        const float4 b0 = *(const float4*)(b + (q << 3));
        const float4 b1 = *(const float4*)(b + (q << 3) + 4);
        float o[8];
        o[0] = fmaf(d, acc[0], b0.x); o[1] = fmaf(d, acc[1], b0.y);
        o[2] = fmaf(d, acc[2], b0.z); o[3] = fmaf(d, acc[3], b0.w);
        o[4] = fmaf(d, acc[4], b1.x); o[5] = fmaf(d, acc[5], b1.y);
        o[6] = fmaf(d, acc[6], b1.z); o[7] = fmaf(d, acc[7], b1.w);
#pragma unroll
        for (int j = 0; j < 8; ++j) o[j] = o[j] > 0.f ? o[j] : 0.f;
        uint4 w;
        w.x = (unsigned)f2bf(o[0]) | ((unsigned)f2bf(o[1]) << 16);
        w.y = (unsigned)f2bf(o[2]) | ((unsigned)f2bf(o[3]) << 16);
        w.z = (unsigned)f2bf(o[4]) | ((unsigned)f2bf(o[5]) << 16);
        w.w = (unsigned)f2bf(o[6]) | ((unsigned)f2bf(o[7]) << 16);
        *(uint4*)(z + ((size_t)node << 6) + (q << 3)) = w;
    }
}

// ---- fused 6-step GRU, v2: 4 waves/block, bf16 weights cached in LDS ----
// each wave handles RB=8 nodes; lane = output feature jj; grid = NN/(RB*GW)
__global__ __launch_bounds__(GW * 64) void gru6_kernel(
        const unsigned short* __restrict__ Zb6,
        const uint2* __restrict__ Aw, const unsigned* __restrict__ Bw,
        const float* __restrict__ bih, const float* __restrict__ bhh,
        float* __restrict__ hfinal) {
    __shared__ uint2 sA[HH * HH];        // 32 KB
    __shared__ unsigned sB[HH * HH];     // 16 KB
    __shared__ float hs[GW][RB][HH];     // 8 KB
    int tid = threadIdx.x;
    int wid = tid >> 6, lane = tid & 63;
    int nbase = (blockIdx.x * GW + wid) * RB;

    // cooperative weight load (once per block)
    for (int i = tid; i < HH * HH; i += GW * 64) { sA[i] = Aw[i]; sB[i] = Bw[i]; }
    __syncthreads();

    float h[RB];
#pragma unroll
    for (int r = 0; r < RB; ++r) h[r] = 0.f;
    float bi0 = bih[lane], bi1 = bih[64 + lane], bi2 = bih[128 + lane];
    float bh0 = bhh[lane], bh1 = bhh[64 + lane], bh2 = bhh[128 + lane];

    for (int t = 0; t < TT; ++t) {
        const unsigned short* zb = Zb6 + (size_t)t * NN * HH;
#pragma unroll
        for (int r = 0; r < RB; ++r) hs[wid][r][lane] = h[r];
        __syncthreads();
        float ir[RB], iz[RB], in_[RB], hr[RB], hz[RB], hn[RB];
#pragma unroll
        for (int r = 0; r < RB; ++r) { ir[r] = iz[r] = in_[r] = hr[r] = hz[r] = hn[r] = 0.f; }
        for (int k0 = 0; k0 < 16; ++k0) {
            uint2 zv[RB]; float4 hv[RB];
#pragma unroll
            for (int r = 0; r < RB; ++r) {
                zv[r] = *(const uint2*)(zb + ((size_t)(nbase + r) << 6) + (k0 << 2));
                hv[r] = *(const float4*)(&hs[wid][r][k0 << 2]);
            }
#pragma unroll
            for (int u = 0; u < 4; ++u) {
                int k = k0 * 4 + u;
                uint2 aw = sA[(k << 6) + lane];
                unsigned bw = sB[(k << 6) + lane];
                float w_ir = bflo(aw.x), w_iz = bfhi(aw.x);
                float w_in = bflo(aw.y), w_hr = bfhi(aw.y);
                float w_hz = bflo(bw),  w_hn = bfhi(bw);
#pragma unroll
                for (int r = 0; r < RB; ++r) {
                    float zk = (u == 0) ? bflo(zv[r].x) : (u == 1) ? bfhi(zv[r].x)
                             : (u == 2) ? bflo(zv[r].y) : bfhi(zv[r].y);
                    float hk = (u == 0) ? hv[r].x : (u == 1) ? hv[r].y
                             : (u == 2) ? hv[r].z : hv[r].w;
                    ir[r]  = fmaf(zk, w_ir, ir[r]);
                    iz[r]  = fmaf(zk, w_iz, iz[r]);
                    in_[r] = fmaf(zk, w_in, in_[r]);
                    hr[r]  = fmaf(hk, w_hr, hr[r]);
                    hz[r]  = fmaf(hk, w_hz, hz[r]);
                    hn[r]  = fmaf(hk, w_hn, hn[r]);
                }
            }
        }
        __syncthreads();  // all reads of hs done before next t overwrites
#pragma unroll
        for (int r = 0; r < RB; ++r) {
            float rr = 1.f / (1.f + expf(-(ir[r] + bi0 + hr[r] + bh0)));
            float zg = 1.f / (1.f + expf(-(iz[r] + bi1 + hz[r] + bh1)));
            float ng = tanhf(in_[r] + bi2 + rr * (hn[r] + bh2));
            h[r] = (1.f - zg) * ng + zg * h[r];
        }
    }
#pragma unroll
    for (int r = 0; r < RB; ++r)
        hfinal[((size_t)(nbase + r) << 6) + lane] = h[r];
}

// ---- fused MLP head: out = sigmoid(relu(h@W3+b3)@W4 + b4) ---------------
__global__ void head_kernel(const float* __restrict__ h, const float* __restrict__ W3,
                            const float* __restrict__ b3, const float* __restrict__ W4,
                            const float* __restrict__ b4, float* __restrict__ out) {
    int nbase = blockIdx.x * RB;
    int lane = threadIdx.x;
    float acc[RB];
#pragma unroll
    for (int r = 0; r < RB; ++r) acc[r] = 0.f;
    for (int k0 = 0; k0 < 16; ++k0) {
        float4 hv[RB];
#pragma unroll
        for (int r = 0; r < RB; ++r)
            hv[r] = ((const float4*)(h + ((size_t)(nbase + r) << 6)))[k0];
#pragma unroll
        for (int u = 0; u < 4; ++u) {
            float w = W3[(k0 * 4 + u) * HH + lane];
#pragma unroll
            for (int r = 0; r < RB; ++r) {
                float hk = (u == 0) ? hv[r].x : (u == 1) ? hv[r].y : (u == 2) ? hv[r].z : hv[r].w;
                acc[r] = fmaf(hk, w, acc[r]);
            }
        }
    }
    float bb = b3[lane], w4 = W4[lane], b40 = b4[0];
#pragma unroll
    for (int r = 0; r < RB; ++r) {
        float v = acc[r] + bb;
        v = v > 0.f ? v : 0.f;
        float s = v * w4;
        s += __shfl_xor(s, 32); s += __shfl_xor(s, 16); s += __shfl_xor(s, 8);
        s += __shfl_xor(s, 4);  s += __shfl_xor(s, 2);  s += __shfl_xor(s, 1);
        if (lane == r) out[nbase + r] = 1.f / (1.f + expf(-(s + b40)));
    }
}

extern "C" void kernel_launch(void* const* d_in, const int* in_sizes, int n_in,
                              void* d_out, int out_size, void* d_ws, size_t ws_size,
                              hipStream_t stream) {
    const float* nf    = (const float*)d_in[0];
    const int*   edges = (const int*)  d_in[1];
    const float* W1  = (const float*)d_in[2];
    const float* b1  = (const float*)d_in[3];
    const float* W2  = (const float*)d_in[4];
    const float* b2  = (const float*)d_in[5];
    const float* wih = (const float*)d_in[6];
    const float* whh = (const float*)d_in[7];
    const float* bih = (const float*)d_in[8];
    const float* bhh = (const float*)d_in[9];
    const float* W3  = (const float*)d_in[10];
    const float* b3  = (const float*)d_in[11];
    const float* W4  = (const float*)d_in[12];
    const float* b4  = (const float*)d_in[13];
    float* out = (float*)d_out;

    // workspace layout
    int* wsi      = (int*)d_ws;
    int* cnt6     = wsi;                              // 6*NN
    int* gcur     = cnt6 + 6 * NN;                    // 6*NBKT (zeroed)
    int* rowptr6  = gcur + 6 * NBKT;                  // 6*(NN+1)
    int* col6     = rowptr6 + 6 * (NN + 1);           // 6*EE
    int* bucketArr= col6 + (size_t)6 * EE;            // 6*NBKT*CAP
    uintptr_t fbase = ((uintptr_t)(bucketArr + (size_t)6 * NBKT * CAP) + 15) & ~(uintptr_t)15;
    uint2* packAw = (uint2*)fbase;                    // 4096 uint2 (32KB)
    unsigned* packBw = (unsigned*)(packAw + HH * HH); // 4096 uint (16KB)
    float* dinv6 = (float*)(packBw + HH * HH);        // 6*NN
    float* Hf    = dinv6 + 6 * NN;                    // NN*HH (final h, fp32)
    unsigned short* Yb    = (unsigned short*)(Hf + (size_t)NN * HH);  // 6*NN*HH bf16
    unsigned short* Y2all = Yb + (size_t)6 * NN * HH;                 // 6*NN*HH bf16
    unsigned short* Zb1   = Y2all + (size_t)6 * NN * HH;              // 6*NN*HH bf16
    unsigned short* Zb2   = Zb1 + (size_t)6 * NN * HH;                // 6*NN*HH bf16

    const int BS  = 256;
    const int gNH = (NN * HH + BS - 1) / BS;   // 5000
    const int gRB = NN / RB;                   // 2500
    const int gG6 = NN / (RB * GW);            // 625
    const int gBIN = (EE + EPB - 1) / EPB;     // 157

    hipMemsetAsync(gcur, 0, 6 * NBKT * sizeof(int), stream);
    pack_gru_kernel<<<(HH * HH + BS - 1) / BS, BS, 0, stream>>>(wih, whh, packAw, packBw);

    bin6_kernel<<<dim3(gBIN, TT), BS, 0, stream>>>(edges, gcur, bucketArr);
    bucket_count6_kernel<<<dim3(NBKT, TT), BS, 0, stream>>>(gcur, bucketArr, cnt6);
    scan6_kernel<<<TT, 1024, 0, stream>>>(cnt6, rowptr6, dinv6);
    regroup6_kernel<<<dim3(NBKT, TT), BS, 0, stream>>>(rowptr6, gcur, bucketArr, col6);
    y1all_kernel<<<dim3(gNH, TT), BS, 0, stream>>>(nf, W1, dinv6, Yb);

    // GCN layer 1 (all t) -> dense (all t) -> GCN layer 2 (all t)
    gather6_kernel<<<dim3(gNH, TT), BS, 0, stream>>>(rowptr6, col6, dinv6, Yb, b1, Zb1);
    y2all_kernel<<<dim3(gRB, TT), 64, 0, stream>>>(Zb1, W2, dinv6, Y2all);
    gather6_kernel<<<dim3(gNH, TT), BS, 0, stream>>>(rowptr6, col6, dinv6, Y2all, b2, Zb2);

    // fused GRU over all 6 timesteps (h in registers, weights in LDS)
    gru6_kernel<<<gG6, GW * 64, 0, stream>>>(Zb2, packAw, packBw, bih, bhh, Hf);

    head_kernel<<<gRB, 64, 0, stream>>>(Hf, W3, b3, W4, b4, out);
}